// Round 1
// baseline (253.234 us; speedup 1.0000x reference)
//
#include <hip/hip_runtime.h>

typedef __attribute__((ext_vector_type(8))) short bf16x8;
typedef __attribute__((ext_vector_type(4))) float f32x4;

__device__ __forceinline__ ushort f2bf(float f) {
    union { float f; unsigned u; } x; x.f = f;
    unsigned r = x.u + 0x7fffu + ((x.u >> 16) & 1u);
    return (ushort)(r >> 16);
}

__device__ __forceinline__ void async16(const void* g, void* l) {
    __builtin_amdgcn_global_load_lds(
        (const __attribute__((address_space(1))) void*)g,
        (__attribute__((address_space(3))) void*)l, 16, 0, 0);
}

__device__ __forceinline__ f32x4 mfma16(bf16x8 a, bf16x8 b, f32x4 c) {
    return __builtin_amdgcn_mfma_f32_16x16x32_bf16(a, b, c, 0, 0, 0);
}

__device__ __forceinline__ f32x4 zero4() { f32x4 z = {0.f, 0.f, 0.f, 0.f}; return z; }

__device__ __forceinline__ float rmax16(float v) {
    v = fmaxf(v, __shfl_xor(v, 1));
    v = fmaxf(v, __shfl_xor(v, 2));
    v = fmaxf(v, __shfl_xor(v, 4));
    v = fmaxf(v, __shfl_xor(v, 8));
    return v;
}
__device__ __forceinline__ float rsum16(float v) {
    v += __shfl_xor(v, 1);
    v += __shfl_xor(v, 2);
    v += __shfl_xor(v, 4);
    v += __shfl_xor(v, 8);
    return v;
}

// -------- fp32 -> bf16 conversion, 4 elems/thread --------
__global__ void cvt_kernel(const float* __restrict__ in, ushort* __restrict__ out, int n4) {
    int i = blockIdx.x * 256 + threadIdx.x;
    if (i >= n4) return;
    float4 v = ((const float4*)in)[i];
    ushort4 o;
    o.x = f2bf(v.x); o.y = f2bf(v.y); o.z = f2bf(v.z); o.w = f2bf(v.w);
    ((ushort4*)out)[i] = o;
}

// -------- GEMM: out = A @ W^T  (A: [4096][1024] bf16, W: [1024][1024] bf16) --------
// MODE 0: write bf16 head-layout [B=2][H=16][S=2048][64] with scale
// MODE 1: write fp32 [4096][1024] + bias
template<int MODE>
__global__ __launch_bounds__(256) void gemm_bt(
    const ushort* __restrict__ A, const ushort* __restrict__ W,
    ushort* __restrict__ outb, float* __restrict__ outf,
    const float* __restrict__ bias, float scale)
{
    __shared__ __align__(16) char smem[32768];
    char* As = smem;
    char* Bs = smem + 16384;
    const int tid = threadIdx.x;
    const int lane = tid & 63;
    const int wid  = tid >> 6;
    const int wr = wid >> 1, wc = wid & 1;
    const int bm = blockIdx.x, bn = blockIdx.y;
    const int l15 = lane & 15, g = lane >> 4;

    f32x4 acc[4][4];
    #pragma unroll
    for (int i = 0; i < 4; ++i)
        #pragma unroll
        for (int j = 0; j < 4; ++j) acc[i][j] = zero4();

    for (int kt = 0; kt < 16; ++kt) {
        __syncthreads();
        // stage 128x64 bf16 tiles of A and W; LDS linear dest, XOR-preswizzled source
        #pragma unroll
        for (int it = 0; it < 4; ++it) {
            int c = it * 256 + tid;          // 16B chunk index, 8 chunks per row
            int row = c >> 3;
            int inner = c & 7;
            int srcoff = (inner ^ (row & 7)) * 16;
            const char* srcA = (const char*)A + (size_t)(bm * 128 + row) * 2048 + kt * 128 + srcoff;
            async16(srcA, As + c * 16);
            const char* srcB = (const char*)W + (size_t)(bn * 128 + row) * 2048 + kt * 128 + srcoff;
            async16(srcB, Bs + c * 16);
        }
        __syncthreads();

        bf16x8 af[4][2], bfr[4][2];
        #pragma unroll
        for (int mt = 0; mt < 4; ++mt)
            #pragma unroll
            for (int ks = 0; ks < 2; ++ks) {
                int row = wr * 64 + mt * 16 + l15;
                int byte = (row * 128 + ks * 64 + g * 16) ^ ((row & 7) << 4);
                af[mt][ks] = *(const bf16x8*)(As + byte);
            }
        #pragma unroll
        for (int nt = 0; nt < 4; ++nt)
            #pragma unroll
            for (int ks = 0; ks < 2; ++ks) {
                int row = wc * 64 + nt * 16 + l15;
                int byte = (row * 128 + ks * 64 + g * 16) ^ ((row & 7) << 4);
                bfr[nt][ks] = *(const bf16x8*)(Bs + byte);
            }
        #pragma unroll
        for (int mt = 0; mt < 4; ++mt)
            #pragma unroll
            for (int nt = 0; nt < 4; ++nt) {
                acc[mt][nt] = mfma16(af[mt][0], bfr[nt][0], acc[mt][nt]);
                acc[mt][nt] = mfma16(af[mt][1], bfr[nt][1], acc[mt][nt]);
            }
    }

    #pragma unroll
    for (int mt = 0; mt < 4; ++mt)
        #pragma unroll
        for (int nt = 0; nt < 4; ++nt)
            #pragma unroll
            for (int j = 0; j < 4; ++j) {
                int m = bm * 128 + wr * 64 + mt * 16 + g * 4 + j;
                int n = bn * 128 + wc * 64 + nt * 16 + l15;
                float v = acc[mt][nt][j];
                if (MODE == 0) {
                    int b = m >> 11, s = m & 2047, h = n >> 6, d = n & 63;
                    outb[(((size_t)(b * 16 + h)) * 2048 + s) * 64 + d] = f2bf(v * scale);
                } else {
                    outf[(size_t)m * 1024 + n] = v + bias[n];
                }
            }
}

// -------- causal flash attention over head-layout bf16 tensors --------
// grid (16 q-tiles, 32 bh). block 256 = 4 waves x 32 q-rows. KV tile 64.
__global__ __launch_bounds__(256) void attn_kernel(
    const ushort* __restrict__ qh, const ushort* __restrict__ kh,
    const ushort* __restrict__ vh, ushort* __restrict__ yb)
{
    __shared__ __align__(16) char smem[32768];
    char* Ks  = smem;            // 64x64 bf16, XOR-swizzled
    char* Vts = smem + 8192;     // V^T 64(d) x 64(kv) bf16, XOR-swizzled
    const int tid = threadIdx.x;
    const int lane = tid & 63, wid = tid >> 6;
    char* Ps = smem + 16384 + wid * 4096;   // per-wave P 32x64 bf16, swizzled
    const int l15 = lane & 15, g = lane >> 4;
    const int bh = blockIdx.y;
    const int q0 = blockIdx.x * 128;
    const size_t base = (size_t)bh * 2048 * 64;   // element offset in [BH][S][64]
    const int qrw = q0 + wid * 32;

    // hoist Q fragments (Q pre-scaled by 1/8 at projection)
    bf16x8 qf[2][2];
    #pragma unroll
    for (int mt = 0; mt < 2; ++mt)
        #pragma unroll
        for (int ks = 0; ks < 2; ++ks) {
            int r = qrw + mt * 16 + l15;
            qf[mt][ks] = *(const bf16x8*)((const char*)qh + (base + (size_t)r * 64) * 2 + ks * 64 + g * 16);
        }

    f32x4 o[2][4];
    float m_run[2][4], l_run[2][4];
    #pragma unroll
    for (int mt = 0; mt < 2; ++mt) {
        #pragma unroll
        for (int dt = 0; dt < 4; ++dt) o[mt][dt] = zero4();
        #pragma unroll
        for (int j = 0; j < 4; ++j) { m_run[mt][j] = -1e30f; l_run[mt][j] = 0.0f; }
    }

    const int nkv = q0 / 64 + 2;
    for (int t = 0; t < nkv; ++t) {
        const int kv0 = t * 64;
        __syncthreads();
        // stage K tile via global_load_lds (linear dest, preswizzled source)
        #pragma unroll
        for (int it = 0; it < 2; ++it) {
            int c = it * 256 + tid;
            int row = c >> 3, inner = c & 7;
            const char* src = (const char*)kh + (base + (size_t)(kv0 + row) * 64) * 2 + ((inner ^ (row & 7)) * 16);
            async16(src, Ks + c * 16);
        }
        // stage V^T (register transpose, swizzled scalar writes)
        #pragma unroll
        for (int it = 0; it < 2; ++it) {
            int c = it * 256 + tid;
            int kvr = c >> 3, d0 = (c & 7) * 8;
            uint4 vd = *(const uint4*)((const char*)vh + (base + (size_t)(kv0 + kvr) * 64) * 2 + d0 * 2);
            const ushort* pv = (const ushort*)&vd;
            #pragma unroll
            for (int e = 0; e < 8; ++e) {
                int d = d0 + e;
                int byte = (d * 128 + kvr * 2) ^ ((d & 7) << 4);
                *(ushort*)(Vts + byte) = pv[e];
            }
        }
        __syncthreads();

        if (kv0 <= qrw + 31) {
            // QK^T
            bf16x8 kf[4][2];
            #pragma unroll
            for (int nt = 0; nt < 4; ++nt)
                #pragma unroll
                for (int ks = 0; ks < 2; ++ks) {
                    int row = nt * 16 + l15;
                    int byte = (row * 128 + ks * 64 + g * 16) ^ ((row & 7) << 4);
                    kf[nt][ks] = *(const bf16x8*)(Ks + byte);
                }
            f32x4 s[2][4];
            #pragma unroll
            for (int mt = 0; mt < 2; ++mt)
                #pragma unroll
                for (int nt = 0; nt < 4; ++nt) {
                    s[mt][nt] = zero4();
                    s[mt][nt] = mfma16(qf[mt][0], kf[nt][0], s[mt][nt]);
                    s[mt][nt] = mfma16(qf[mt][1], kf[nt][1], s[mt][nt]);
                }
            // causal mask on diagonal-overlapping tiles
            if (kv0 + 63 > qrw) {
                #pragma unroll
                for (int mt = 0; mt < 2; ++mt)
                    #pragma unroll
                    for (int nt = 0; nt < 4; ++nt)
                        #pragma unroll
                        for (int j = 0; j < 4; ++j) {
                            int q  = qrw + mt * 16 + g * 4 + j;
                            int kv = kv0 + nt * 16 + l15;
                            if (kv > q) s[mt][nt][j] = -1e30f;
                        }
            }
            // wave-parallel online softmax (16-lane groups hold one q-row)
            #pragma unroll
            for (int mt = 0; mt < 2; ++mt)
                #pragma unroll
                for (int j = 0; j < 4; ++j) {
                    float mx = fmaxf(fmaxf(s[mt][0][j], s[mt][1][j]),
                                     fmaxf(s[mt][2][j], s[mt][3][j]));
                    mx = rmax16(mx);
                    float mo = m_run[mt][j];
                    float mn = fmaxf(mo, mx);
                    float corr = __expf(mo - mn);
                    float sum = 0.0f;
                    #pragma unroll
                    for (int nt = 0; nt < 4; ++nt) {
                        float p = __expf(s[mt][nt][j] - mn);
                        s[mt][nt][j] = p;
                        sum += p;
                    }
                    sum = rsum16(sum);
                    l_run[mt][j] = l_run[mt][j] * corr + sum;
                    m_run[mt][j] = mn;
                    #pragma unroll
                    for (int dt = 0; dt < 4; ++dt) o[mt][dt][j] *= corr;
                }
            // P -> per-wave LDS (D-layout scatter, A-layout gather)
            #pragma unroll
            for (int mt = 0; mt < 2; ++mt)
                #pragma unroll
                for (int nt = 0; nt < 4; ++nt)
                    #pragma unroll
                    for (int j = 0; j < 4; ++j) {
                        int pr = mt * 16 + g * 4 + j;
                        int pc = nt * 16 + l15;
                        int byte = (pr * 128 + pc * 2) ^ ((pr & 7) << 4);
                        *(ushort*)(Ps + byte) = f2bf(s[mt][nt][j]);
                    }
            __asm__ volatile("s_waitcnt lgkmcnt(0)" ::: "memory");
            // PV
            bf16x8 pf[2][2], vf[4][2];
            #pragma unroll
            for (int mt = 0; mt < 2; ++mt)
                #pragma unroll
                for (int ks = 0; ks < 2; ++ks) {
                    int pr = mt * 16 + l15;
                    int byte = (pr * 128 + ks * 64 + g * 16) ^ ((pr & 7) << 4);
                    pf[mt][ks] = *(const bf16x8*)(Ps + byte);
                }
            #pragma unroll
            for (int dt = 0; dt < 4; ++dt)
                #pragma unroll
                for (int ks = 0; ks < 2; ++ks) {
                    int vr = dt * 16 + l15;
                    int byte = (vr * 128 + ks * 64 + g * 16) ^ ((vr & 7) << 4);
                    vf[dt][ks] = *(const bf16x8*)(Vts + byte);
                }
            #pragma unroll
            for (int mt = 0; mt < 2; ++mt)
                #pragma unroll
                for (int dt = 0; dt < 4; ++dt) {
                    o[mt][dt] = mfma16(pf[mt][0], vf[dt][0], o[mt][dt]);
                    o[mt][dt] = mfma16(pf[mt][1], vf[dt][1], o[mt][dt]);
                }
        }
    }

    // epilogue: normalize and write [B][S][1024] bf16
    const int b = bh >> 4, h = bh & 15;
    #pragma unroll
    for (int mt = 0; mt < 2; ++mt) {
        float inv[4];
        #pragma unroll
        for (int j = 0; j < 4; ++j) inv[j] = 1.0f / l_run[mt][j];
        #pragma unroll
        for (int dt = 0; dt < 4; ++dt)
            #pragma unroll
            for (int j = 0; j < 4; ++j) {
                int srow = qrw + mt * 16 + g * 4 + j;
                int dcol = dt * 16 + l15;
                yb[((size_t)(b * 2048 + srow)) * 1024 + h * 64 + dcol] = f2bf(o[mt][dt][j] * inv[j]);
            }
    }
}

extern "C" void kernel_launch(void* const* d_in, const int* in_sizes, int n_in,
                              void* d_out, int out_size, void* d_ws, size_t ws_size,
                              hipStream_t stream)
{
    const size_t MD = 4096ull * 1024;   // B*S x d_model elements
    const size_t WD = 1024ull * 1024;
    ushort* ws  = (ushort*)d_ws;
    ushort* Qb  = ws;
    ushort* Kb  = Qb + MD;
    ushort* Vb  = Kb + MD;
    ushort* qhb = Vb + MD;
    ushort* khb = qhb + MD;
    ushort* vhb = khb + MD;
    ushort* WQb = vhb + MD;
    ushort* WKb = WQb + WD;
    ushort* WVb = WKb + WD;
    ushort* Wfb = WVb + WD;
    ushort* yb  = Qb;   // alias: Qb is dead after the Q projection GEMM

    auto cvt = [&](const void* in, ushort* out, size_t n) {
        int n4 = (int)(n / 4);
        cvt_kernel<<<(n4 + 255) / 256, 256, 0, stream>>>((const float*)in, out, n4);
    };
    cvt(d_in[0], Qb, MD);
    cvt(d_in[1], Kb, MD);
    cvt(d_in[2], Vb, MD);
    cvt(d_in[3], WQb, WD);
    cvt(d_in[4], WKb, WD);
    cvt(d_in[5], WVb, WD);
    cvt(d_in[6], Wfb, WD);

    dim3 gg(32, 8);
    gemm_bt<0><<<gg, 256, 0, stream>>>(Qb, WQb, qhb, nullptr, nullptr, 0.125f);
    gemm_bt<0><<<gg, 256, 0, stream>>>(Kb, WKb, khb, nullptr, nullptr, 1.0f);
    gemm_bt<0><<<gg, 256, 0, stream>>>(Vb, WVb, vhb, nullptr, nullptr, 1.0f);
    attn_kernel<<<dim3(16, 32), 256, 0, stream>>>(qhb, khb, vhb, yb);
    gemm_bt<1><<<gg, 256, 0, stream>>>(yb, Wfb, nullptr, (float*)d_out, (const float*)d_in[7], 1.0f);
}

// Round 2
// 194.606 us; speedup vs baseline: 1.3013x; 1.3013x over previous
//
#include <hip/hip_runtime.h>

typedef __attribute__((ext_vector_type(8))) short bf16x8;
typedef __attribute__((ext_vector_type(4))) float f32x4;

__device__ __forceinline__ ushort f2bf(float f) {
    union { float f; unsigned u; } x; x.f = f;
    unsigned r = x.u + 0x7fffu + ((x.u >> 16) & 1u);
    return (ushort)(r >> 16);
}

__device__ __forceinline__ void async16(const void* g, void* l) {
    __builtin_amdgcn_global_load_lds(
        (const __attribute__((address_space(1))) void*)g,
        (__attribute__((address_space(3))) void*)l, 16, 0, 0);
}

__device__ __forceinline__ f32x4 mfma16(bf16x8 a, bf16x8 b, f32x4 c) {
    return __builtin_amdgcn_mfma_f32_16x16x32_bf16(a, b, c, 0, 0, 0);
}

__device__ __forceinline__ f32x4 zero4() { f32x4 z = {0.f, 0.f, 0.f, 0.f}; return z; }

__device__ __forceinline__ float rmax16(float v) {
    v = fmaxf(v, __shfl_xor(v, 1));
    v = fmaxf(v, __shfl_xor(v, 2));
    v = fmaxf(v, __shfl_xor(v, 4));
    v = fmaxf(v, __shfl_xor(v, 8));
    return v;
}
__device__ __forceinline__ float rsum16(float v) {
    v += __shfl_xor(v, 1);
    v += __shfl_xor(v, 2);
    v += __shfl_xor(v, 4);
    v += __shfl_xor(v, 8);
    return v;
}

// -------- fused fp32 -> bf16 conversion for all 7 tensors, one launch --------
__global__ void cvt7_kernel(
    const float* __restrict__ s0, const float* __restrict__ s1, const float* __restrict__ s2,
    const float* __restrict__ s3, const float* __restrict__ s4, const float* __restrict__ s5,
    const float* __restrict__ s6,
    ushort* __restrict__ d0, ushort* __restrict__ d1, ushort* __restrict__ d2,
    ushort* __restrict__ d3, ushort* __restrict__ d4, ushort* __restrict__ d5,
    ushort* __restrict__ d6)
{
    int y = blockIdx.y;
    const float* s; ushort* d; int n4;
    if      (y == 0) { s = s0; d = d0; n4 = 1048576; }
    else if (y == 1) { s = s1; d = d1; n4 = 1048576; }
    else if (y == 2) { s = s2; d = d2; n4 = 1048576; }
    else if (y == 3) { s = s3; d = d3; n4 = 262144; }
    else if (y == 4) { s = s4; d = d4; n4 = 262144; }
    else if (y == 5) { s = s5; d = d5; n4 = 262144; }
    else             { s = s6; d = d6; n4 = 262144; }
    int i = blockIdx.x * 256 + threadIdx.x;
    if (i >= n4) return;
    float4 v = ((const float4*)s)[i];
    ushort4 o;
    o.x = f2bf(v.x); o.y = f2bf(v.y); o.z = f2bf(v.z); o.w = f2bf(v.w);
    ((ushort4*)d)[i] = o;
}

// -------- GEMM: out = A @ W^T  (A: [4096][1024] bf16, W: [1024][1024] bf16) --------
// Double-buffered LDS staging (2-phase). MODE 0: bf16 head-layout out. MODE 1: fp32 + bias.
template<int MODE>
__global__ __launch_bounds__(256) void gemm_bt(
    const ushort* __restrict__ A, const ushort* __restrict__ W,
    ushort* __restrict__ outb, float* __restrict__ outf,
    const float* __restrict__ bias, float scale)
{
    __shared__ __align__(16) char smem[65536];
    const int tid = threadIdx.x;
    const int lane = tid & 63;
    const int wid  = tid >> 6;
    const int wr = wid >> 1, wc = wid & 1;
    const int bm = blockIdx.x, bn = blockIdx.y;
    const int l15 = lane & 15, g = lane >> 4;

    auto stage = [&](int kt, int b) {
        char* As = smem + b * 32768;
        char* Bs = smem + b * 32768 + 16384;
        #pragma unroll
        for (int it = 0; it < 4; ++it) {
            int c = it * 256 + tid;          // 16B chunk, 8 per 64-elem row
            int row = c >> 3;
            int inner = c & 7;
            int srcoff = (inner ^ (row & 7)) * 16;
            async16((const char*)A + (size_t)(bm * 128 + row) * 2048 + kt * 128 + srcoff,
                    As + c * 16);
            async16((const char*)W + (size_t)(bn * 128 + row) * 2048 + kt * 128 + srcoff,
                    Bs + c * 16);
        }
    };

    f32x4 acc[4][4];
    #pragma unroll
    for (int i = 0; i < 4; ++i)
        #pragma unroll
        for (int j = 0; j < 4; ++j) acc[i][j] = zero4();

    stage(0, 0);
    __syncthreads();

    for (int kt = 0; kt < 16; ++kt) {
        const int cur = kt & 1;
        if (kt < 15) stage(kt + 1, cur ^ 1);

        const char* As = smem + cur * 32768;
        const char* Bs = smem + cur * 32768 + 16384;
        bf16x8 af[4][2], bfr[4][2];
        #pragma unroll
        for (int mt = 0; mt < 4; ++mt)
            #pragma unroll
            for (int ks = 0; ks < 2; ++ks) {
                int row = wr * 64 + mt * 16 + l15;
                int byte = (row * 128 + ks * 64 + g * 16) ^ ((row & 7) << 4);
                af[mt][ks] = *(const bf16x8*)(As + byte);
            }
        #pragma unroll
        for (int nt = 0; nt < 4; ++nt)
            #pragma unroll
            for (int ks = 0; ks < 2; ++ks) {
                int row = wc * 64 + nt * 16 + l15;
                int byte = (row * 128 + ks * 64 + g * 16) ^ ((row & 7) << 4);
                bfr[nt][ks] = *(const bf16x8*)(Bs + byte);
            }
        #pragma unroll
        for (int mt = 0; mt < 4; ++mt)
            #pragma unroll
            for (int nt = 0; nt < 4; ++nt) {
                acc[mt][nt] = mfma16(af[mt][0], bfr[nt][0], acc[mt][nt]);
                acc[mt][nt] = mfma16(af[mt][1], bfr[nt][1], acc[mt][nt]);
            }
        __syncthreads();
    }

    #pragma unroll
    for (int mt = 0; mt < 4; ++mt)
        #pragma unroll
        for (int nt = 0; nt < 4; ++nt)
            #pragma unroll
            for (int j = 0; j < 4; ++j) {
                int m = bm * 128 + wr * 64 + mt * 16 + g * 4 + j;
                int n = bn * 128 + wc * 64 + nt * 16 + l15;
                float v = acc[mt][nt][j];
                if (MODE == 0) {
                    int b = m >> 11, s = m & 2047, h = n >> 6, d = n & 63;
                    outb[(((size_t)(b * 16 + h)) * 2048 + s) * 64 + d] = f2bf(v * scale);
                } else {
                    outf[(size_t)m * 1024 + n] = v + bias[n];
                }
            }
}

// -------- causal flash attention, double-buffered K/V staging --------
// grid (16 x-pairs, 32 bh). block 256 = 4 waves x 32 q-rows. KV tile 64.
// Work-balance: qt = (bh<16) ? x : 15-x so stride-256 colocated blocks total 34 iters.
__global__ __launch_bounds__(256) void attn_kernel(
    const ushort* __restrict__ qh, const ushort* __restrict__ kh,
    const ushort* __restrict__ vh, ushort* __restrict__ yb)
{
    __shared__ __align__(16) char smem[49152];
    // layout: K0 @0, K1 @8192, Vt0 @16384, Vt1 @24576, Ps @32768 + wid*4096
    const int tid = threadIdx.x;
    const int lane = tid & 63, wid = tid >> 6;
    const int l15 = lane & 15, g = lane >> 4;
    const int bh = blockIdx.y;
    const int qt = (bh < 16) ? (int)blockIdx.x : 15 - (int)blockIdx.x;
    const int q0 = qt * 128;
    const size_t base = (size_t)bh * 2048 * 64;   // element offset in [BH][S][64]
    const int qrw = q0 + wid * 32;
    char* Ps = smem + 32768 + wid * 4096;

    auto stageK = [&](int t, int b) {
        char* Ks = smem + b * 8192;
        #pragma unroll
        for (int it = 0; it < 2; ++it) {
            int c = it * 256 + tid;
            int row = c >> 3, inner = c & 7;
            const char* src = (const char*)kh + (base + (size_t)(t * 64 + row) * 64) * 2
                              + ((inner ^ (row & 7)) * 16);
            async16(src, Ks + c * 16);
        }
    };
    auto loadV = [&](int t, uint4* vd) {
        #pragma unroll
        for (int it = 0; it < 2; ++it) {
            int c = it * 256 + tid;
            int kvr = c >> 3, d0 = (c & 7) * 8;
            vd[it] = *(const uint4*)((const char*)vh + (base + (size_t)(t * 64 + kvr) * 64) * 2 + d0 * 2);
        }
    };
    auto writeV = [&](int b, const uint4* vd) {
        char* Vts = smem + 16384 + b * 8192;
        #pragma unroll
        for (int it = 0; it < 2; ++it) {
            int c = it * 256 + tid;
            int kvr = c >> 3, d0 = (c & 7) * 8;
            const ushort* pv = (const ushort*)&vd[it];
            #pragma unroll
            for (int e = 0; e < 8; ++e) {
                int d = d0 + e;
                int byte = (d * 128 + kvr * 2) ^ ((d & 7) << 4);
                *(ushort*)(Vts + byte) = pv[e];
            }
        }
    };

    // hoist Q fragments (Q pre-scaled by 1/8 at projection)
    bf16x8 qf[2][2];
    #pragma unroll
    for (int mt = 0; mt < 2; ++mt)
        #pragma unroll
        for (int ks = 0; ks < 2; ++ks) {
            int r = qrw + mt * 16 + l15;
            qf[mt][ks] = *(const bf16x8*)((const char*)qh + (base + (size_t)r * 64) * 2 + ks * 64 + g * 16);
        }

    f32x4 o[2][4];
    float m_run[2][4], l_run[2][4];
    #pragma unroll
    for (int mt = 0; mt < 2; ++mt) {
        #pragma unroll
        for (int dt = 0; dt < 4; ++dt) o[mt][dt] = zero4();
        #pragma unroll
        for (int j = 0; j < 4; ++j) { m_run[mt][j] = -1e30f; l_run[mt][j] = 0.0f; }
    }

    const int nkv = qt * 2 + 2;
    uint4 vd[2];
    stageK(0, 0);
    loadV(0, vd);
    writeV(0, vd);
    __syncthreads();

    for (int t = 0; t < nkv; ++t) {
        const int kv0 = t * 64;
        const int cur = t & 1;
        const bool pf = (t + 1 < nkv);
        if (pf) { stageK(t + 1, cur ^ 1); loadV(t + 1, vd); }

        if (kv0 <= qrw + 31) {
            const char* Ks  = smem + cur * 8192;
            const char* Vts = smem + 16384 + cur * 8192;
            // QK^T
            bf16x8 kf[4][2];
            #pragma unroll
            for (int nt = 0; nt < 4; ++nt)
                #pragma unroll
                for (int ks = 0; ks < 2; ++ks) {
                    int row = nt * 16 + l15;
                    int byte = (row * 128 + ks * 64 + g * 16) ^ ((row & 7) << 4);
                    kf[nt][ks] = *(const bf16x8*)(Ks + byte);
                }
            f32x4 s[2][4];
            #pragma unroll
            for (int mt = 0; mt < 2; ++mt)
                #pragma unroll
                for (int nt = 0; nt < 4; ++nt) {
                    s[mt][nt] = zero4();
                    s[mt][nt] = mfma16(qf[mt][0], kf[nt][0], s[mt][nt]);
                    s[mt][nt] = mfma16(qf[mt][1], kf[nt][1], s[mt][nt]);
                }
            // causal mask on diagonal-overlapping tiles
            if (kv0 + 63 > qrw) {
                #pragma unroll
                for (int mt = 0; mt < 2; ++mt)
                    #pragma unroll
                    for (int nt = 0; nt < 4; ++nt)
                        #pragma unroll
                        for (int j = 0; j < 4; ++j) {
                            int q  = qrw + mt * 16 + g * 4 + j;
                            int kv = kv0 + nt * 16 + l15;
                            if (kv > q) s[mt][nt][j] = -1e30f;
                        }
            }
            // wave-parallel online softmax (16-lane groups hold one q-row)
            #pragma unroll
            for (int mt = 0; mt < 2; ++mt)
                #pragma unroll
                for (int j = 0; j < 4; ++j) {
                    float mx = fmaxf(fmaxf(s[mt][0][j], s[mt][1][j]),
                                     fmaxf(s[mt][2][j], s[mt][3][j]));
                    mx = rmax16(mx);
                    float mo = m_run[mt][j];
                    float mn = fmaxf(mo, mx);
                    float corr = __expf(mo - mn);
                    float sum = 0.0f;
                    #pragma unroll
                    for (int nt = 0; nt < 4; ++nt) {
                        float p = __expf(s[mt][nt][j] - mn);
                        s[mt][nt][j] = p;
                        sum += p;
                    }
                    sum = rsum16(sum);
                    l_run[mt][j] = l_run[mt][j] * corr + sum;
                    m_run[mt][j] = mn;
                    #pragma unroll
                    for (int dt = 0; dt < 4; ++dt) o[mt][dt][j] *= corr;
                }
            // P -> per-wave LDS (D-layout scatter, A-layout gather)
            #pragma unroll
            for (int mt = 0; mt < 2; ++mt)
                #pragma unroll
                for (int nt = 0; nt < 4; ++nt)
                    #pragma unroll
                    for (int j = 0; j < 4; ++j) {
                        int pr = mt * 16 + g * 4 + j;
                        int pc = nt * 16 + l15;
                        int byte = (pr * 128 + pc * 2) ^ ((pr & 7) << 4);
                        *(ushort*)(Ps + byte) = f2bf(s[mt][nt][j]);
                    }
            __asm__ volatile("s_waitcnt lgkmcnt(0)" ::: "memory");
            // PV
            bf16x8 pf[2][2], vf[4][2];
            #pragma unroll
            for (int mt = 0; mt < 2; ++mt)
                #pragma unroll
                for (int ks = 0; ks < 2; ++ks) {
                    int pr = mt * 16 + l15;
                    int byte = (pr * 128 + ks * 64 + g * 16) ^ ((pr & 7) << 4);
                    pf[mt][ks] = *(const bf16x8*)(Ps + byte);
                }
            #pragma unroll
            for (int dt = 0; dt < 4; ++dt)
                #pragma unroll
                for (int ks = 0; ks < 2; ++ks) {
                    int vr = dt * 16 + l15;
                    int byte = (vr * 128 + ks * 64 + g * 16) ^ ((vr & 7) << 4);
                    vf[dt][ks] = *(const bf16x8*)(Vts + byte);
                }
            #pragma unroll
            for (int mt = 0; mt < 2; ++mt)
                #pragma unroll
                for (int dt = 0; dt < 4; ++dt) {
                    o[mt][dt] = mfma16(pf[mt][0], vf[dt][0], o[mt][dt]);
                    o[mt][dt] = mfma16(pf[mt][1], vf[dt][1], o[mt][dt]);
                }
        }

        if (pf) writeV(cur ^ 1, vd);
        __syncthreads();
    }

    // epilogue: normalize and write [B][S][1024] bf16
    const int b = bh >> 4, h = bh & 15;
    #pragma unroll
    for (int mt = 0; mt < 2; ++mt) {
        float inv[4];
        #pragma unroll
        for (int j = 0; j < 4; ++j) inv[j] = 1.0f / l_run[mt][j];
        #pragma unroll
        for (int dt = 0; dt < 4; ++dt)
            #pragma unroll
            for (int j = 0; j < 4; ++j) {
                int srow = qrw + mt * 16 + g * 4 + j;
                int dcol = dt * 16 + l15;
                yb[((size_t)(b * 2048 + srow)) * 1024 + h * 64 + dcol] = f2bf(o[mt][dt][j] * inv[j]);
            }
    }
}

extern "C" void kernel_launch(void* const* d_in, const int* in_sizes, int n_in,
                              void* d_out, int out_size, void* d_ws, size_t ws_size,
                              hipStream_t stream)
{
    const size_t MD = 4096ull * 1024;   // B*S x d_model elements
    const size_t WD = 1024ull * 1024;
    ushort* ws  = (ushort*)d_ws;
    ushort* Qb  = ws;
    ushort* Kb  = Qb + MD;
    ushort* Vb  = Kb + MD;
    ushort* qhb = Vb + MD;
    ushort* khb = qhb + MD;
    ushort* vhb = khb + MD;
    ushort* WQb = vhb + MD;
    ushort* WKb = WQb + WD;
    ushort* WVb = WKb + WD;
    ushort* Wfb = WVb + WD;
    ushort* yb  = Qb;   // alias: Qb is dead after the Q projection GEMM

    cvt7_kernel<<<dim3(4096, 7), 256, 0, stream>>>(
        (const float*)d_in[0], (const float*)d_in[1], (const float*)d_in[2],
        (const float*)d_in[3], (const float*)d_in[4], (const float*)d_in[5],
        (const float*)d_in[6],
        Qb, Kb, Vb, WQb, WKb, WVb, Wfb);

    dim3 gg(32, 8);
    gemm_bt<0><<<gg, 256, 0, stream>>>(Qb, WQb, qhb, nullptr, nullptr, 0.125f);
    gemm_bt<0><<<gg, 256, 0, stream>>>(Kb, WKb, khb, nullptr, nullptr, 1.0f);
    gemm_bt<0><<<gg, 256, 0, stream>>>(Vb, WVb, vhb, nullptr, nullptr, 1.0f);
    attn_kernel<<<dim3(16, 32), 256, 0, stream>>>(qhb, khb, vhb, yb);
    gemm_bt<1><<<gg, 256, 0, stream>>>(yb, Wfb, nullptr, (float*)d_out, (const float*)d_in[7], 1.0f);
}

// Round 3
// 121.148 us; speedup vs baseline: 2.0903x; 1.6063x over previous
//
#include <hip/hip_runtime.h>

typedef __attribute__((ext_vector_type(8))) short bf16x8;
typedef __attribute__((ext_vector_type(4))) float f32x4;
typedef __attribute__((ext_vector_type(16))) float f32x16;

__device__ __forceinline__ ushort f2bf(float f) {
    union { float f; unsigned u; } x; x.f = f;
    unsigned r = x.u + 0x7fffu + ((x.u >> 16) & 1u);
    return (ushort)(r >> 16);
}

__device__ __forceinline__ void async16(const void* g, void* l) {
    __builtin_amdgcn_global_load_lds(
        (const __attribute__((address_space(1))) void*)g,
        (__attribute__((address_space(3))) void*)l, 16, 0, 0);
}

__device__ __forceinline__ f32x4 mfma16(bf16x8 a, bf16x8 b, f32x4 c) {
    return __builtin_amdgcn_mfma_f32_16x16x32_bf16(a, b, c, 0, 0, 0);
}
__device__ __forceinline__ f32x16 mfma32(bf16x8 a, bf16x8 b, f32x16 c) {
    return __builtin_amdgcn_mfma_f32_32x32x16_bf16(a, b, c, 0, 0, 0);
}

__device__ __forceinline__ f32x4 zero4() { f32x4 z = {0.f, 0.f, 0.f, 0.f}; return z; }

// -------- fused fp32 -> bf16 conversion for all 7 tensors, one launch --------
__global__ void cvt7_kernel(
    const float* __restrict__ s0, const float* __restrict__ s1, const float* __restrict__ s2,
    const float* __restrict__ s3, const float* __restrict__ s4, const float* __restrict__ s5,
    const float* __restrict__ s6,
    ushort* __restrict__ d0, ushort* __restrict__ d1, ushort* __restrict__ d2,
    ushort* __restrict__ d3, ushort* __restrict__ d4, ushort* __restrict__ d5,
    ushort* __restrict__ d6)
{
    int y = blockIdx.y;
    const float* s; ushort* d; int n4;
    if      (y == 0) { s = s0; d = d0; n4 = 1048576; }
    else if (y == 1) { s = s1; d = d1; n4 = 1048576; }
    else if (y == 2) { s = s2; d = d2; n4 = 1048576; }
    else if (y == 3) { s = s3; d = d3; n4 = 262144; }
    else if (y == 4) { s = s4; d = d4; n4 = 262144; }
    else if (y == 5) { s = s5; d = d5; n4 = 262144; }
    else             { s = s6; d = d6; n4 = 262144; }
    int i = blockIdx.x * 256 + threadIdx.x;
    if (i >= n4) return;
    float4 v = ((const float4*)s)[i];
    ushort4 o;
    o.x = f2bf(v.x); o.y = f2bf(v.y); o.z = f2bf(v.z); o.w = f2bf(v.w);
    ((ushort4*)d)[i] = o;
}

// -------- shared GEMM core: 128x128 tile, BK=64, double-buffered --------
// SWAP=false: acc[mt][nt] = A-rows x W-rows.  SWAP=true: transposed (W-rows x A-rows).
template<bool SWAP>
__device__ __forceinline__ void gemm_core(
    const ushort* __restrict__ A, const ushort* __restrict__ W,
    char* smem, int bm, int bn, int tid, f32x4 acc[4][4])
{
    const int lane = tid & 63;
    const int wid  = tid >> 6;
    const int wr = wid >> 1, wc = wid & 1;
    const int l15 = lane & 15, g = lane >> 4;

    auto stage = [&](int kt, int b) {
        char* As = smem + b * 32768;
        char* Bs = As + 16384;
        #pragma unroll
        for (int it = 0; it < 4; ++it) {
            int c = it * 256 + tid;
            int row = c >> 3;
            int inner = c & 7;
            int srcoff = (inner ^ (row & 7)) * 16;
            async16((const char*)A + (size_t)(bm * 128 + row) * 2048 + kt * 128 + srcoff, As + c * 16);
            async16((const char*)W + (size_t)(bn * 128 + row) * 2048 + kt * 128 + srcoff, Bs + c * 16);
        }
    };

    stage(0, 0);
    __syncthreads();

    for (int kt = 0; kt < 16; ++kt) {
        const int cur = kt & 1;
        if (kt < 15) stage(kt + 1, cur ^ 1);

        const char* As = smem + cur * 32768;
        const char* Bs = As + 16384;
        bf16x8 af[4][2], bfr[4][2];
        #pragma unroll
        for (int mt = 0; mt < 4; ++mt)
            #pragma unroll
            for (int ks = 0; ks < 2; ++ks) {
                int row = wr * 64 + mt * 16 + l15;
                int byte = (row * 128 + ks * 64 + g * 16) ^ ((row & 7) << 4);
                af[mt][ks] = *(const bf16x8*)(As + byte);
            }
        #pragma unroll
        for (int nt = 0; nt < 4; ++nt)
            #pragma unroll
            for (int ks = 0; ks < 2; ++ks) {
                int row = wc * 64 + nt * 16 + l15;
                int byte = (row * 128 + ks * 64 + g * 16) ^ ((row & 7) << 4);
                bfr[nt][ks] = *(const bf16x8*)(Bs + byte);
            }
        #pragma unroll
        for (int mt = 0; mt < 4; ++mt)
            #pragma unroll
            for (int nt = 0; nt < 4; ++nt) {
                if (SWAP) {
                    acc[mt][nt] = mfma16(bfr[nt][0], af[mt][0], acc[mt][nt]);
                    acc[mt][nt] = mfma16(bfr[nt][1], af[mt][1], acc[mt][nt]);
                } else {
                    acc[mt][nt] = mfma16(af[mt][0], bfr[nt][0], acc[mt][nt]);
                    acc[mt][nt] = mfma16(af[mt][1], bfr[nt][1], acc[mt][nt]);
                }
            }
        __syncthreads();
    }
}

// -------- merged QKV projection: grid (96, 8), z = x%3 --------
// z=0: Q -> head layout [bh][s][64], scale 1/8
// z=1: K -> head layout
// z=2: V -> TRANSPOSED head layout [bh][64][2048] (for attn B-frag reads)
__global__ __launch_bounds__(256) void gemm_qkv(
    const ushort* __restrict__ Qb, const ushort* __restrict__ Kb, const ushort* __restrict__ Vb,
    const ushort* __restrict__ WQ, const ushort* __restrict__ WK, const ushort* __restrict__ WV,
    ushort* __restrict__ qhb, ushort* __restrict__ khb, ushort* __restrict__ vhT)
{
    __shared__ __align__(16) char smem[65536];
    const int tid = threadIdx.x;
    const int z  = blockIdx.x % 3;
    const int bm = blockIdx.x / 3;
    const int bn = blockIdx.y;
    const int lane = tid & 63;
    const int wid  = tid >> 6;
    const int wr = wid >> 1, wc = wid & 1;
    const int l15 = lane & 15, g = lane >> 4;

    const ushort* A  = (z == 0) ? Qb : (z == 1) ? Kb : Vb;
    const ushort* Wm = (z == 0) ? WQ : (z == 1) ? WK : WV;

    f32x4 acc[4][4];
    #pragma unroll
    for (int i = 0; i < 4; ++i)
        #pragma unroll
        for (int j = 0; j < 4; ++j) acc[i][j] = zero4();

    if (z == 2) {
        gemm_core<true>(A, Wm, smem, bm, bn, tid, acc);
        // D rows = W rows (d-model index n), cols = A rows (token m)
        #pragma unroll
        for (int mt = 0; mt < 4; ++mt)
            #pragma unroll
            for (int nt = 0; nt < 4; ++nt)
                #pragma unroll
                for (int j = 0; j < 4; ++j) {
                    int n = bn * 128 + wc * 64 + nt * 16 + g * 4 + j;
                    int m = bm * 128 + wr * 64 + mt * 16 + l15;
                    int b = m >> 11, s = m & 2047, h = (n >> 6) & 15, d = n & 63;
                    vhT[(((size_t)(b * 16 + h)) * 64 + d) * 2048 + s] = f2bf(acc[mt][nt][j]);
                }
    } else {
        gemm_core<false>(A, Wm, smem, bm, bn, tid, acc);
        const float scale = (z == 0) ? 0.125f : 1.0f;
        ushort* outb = (z == 0) ? qhb : khb;
        #pragma unroll
        for (int mt = 0; mt < 4; ++mt)
            #pragma unroll
            for (int nt = 0; nt < 4; ++nt)
                #pragma unroll
                for (int j = 0; j < 4; ++j) {
                    int m = bm * 128 + wr * 64 + mt * 16 + g * 4 + j;
                    int n = bn * 128 + wc * 64 + nt * 16 + l15;
                    int b = m >> 11, s = m & 2047, h = n >> 6, d = n & 63;
                    outb[(((size_t)(b * 16 + h)) * 2048 + s) * 64 + d] = f2bf(acc[mt][nt][j] * scale);
                }
    }
}

// -------- final GEMM: out = A @ W^T + bias (fp32 out) --------
__global__ __launch_bounds__(256) void gemm_fc(
    const ushort* __restrict__ A, const ushort* __restrict__ W,
    float* __restrict__ outf, const float* __restrict__ bias)
{
    __shared__ __align__(16) char smem[65536];
    const int tid = threadIdx.x;
    const int lane = tid & 63;
    const int wid  = tid >> 6;
    const int wr = wid >> 1, wc = wid & 1;
    const int l15 = lane & 15, g = lane >> 4;

    f32x4 acc[4][4];
    #pragma unroll
    for (int i = 0; i < 4; ++i)
        #pragma unroll
        for (int j = 0; j < 4; ++j) acc[i][j] = zero4();

    gemm_core<false>(A, W, smem, blockIdx.x, blockIdx.y, tid, acc);

    #pragma unroll
    for (int mt = 0; mt < 4; ++mt)
        #pragma unroll
        for (int nt = 0; nt < 4; ++nt)
            #pragma unroll
            for (int j = 0; j < 4; ++j) {
                int m = blockIdx.x * 128 + wr * 64 + mt * 16 + g * 4 + j;
                int n = blockIdx.y * 128 + wc * 64 + nt * 16 + l15;
                outf[(size_t)m * 1024 + n] = acc[mt][nt][j] + bias[n];
            }
}

// -------- causal flash attention, 32x32 MFMA, in-register softmax --------
// grid (16, 32). block 256 = 4 waves x 32 q-rows. KV tile 64.
// S^T = mfma32(K, Q): lane holds scores for q = lane&31 (kv split across halves).
__global__ __launch_bounds__(256, 2) void attn_kernel(
    const ushort* __restrict__ qh, const ushort* __restrict__ kh,
    const ushort* __restrict__ vhT, ushort* __restrict__ yb)
{
    __shared__ __align__(16) char smem[32768];
    // K0 @0, K1 @8192, Vt0 @16384, Vt1 @24576 (all 64x64 bf16, XOR-swizzled)
    const int tid = threadIdx.x;
    const int lane = tid & 63, wid = tid >> 6;
    const int l31 = lane & 31;
    const int hi  = lane >> 5;
    const int bh = blockIdx.y;
    const int qt = (bh < 16) ? (int)blockIdx.x : 15 - (int)blockIdx.x;
    const int q0 = qt * 128;
    const size_t base = (size_t)bh * 2048 * 64;   // elems; same product for vhT
    const int qrw = q0 + wid * 32;

    auto stageK = [&](int t, int b) {
        char* Ks = smem + b * 8192;
        #pragma unroll
        for (int it = 0; it < 2; ++it) {
            int c = it * 256 + tid;
            int row = c >> 3, inner = c & 7;
            async16((const char*)kh + (base + (size_t)(t * 64 + row) * 64) * 2 + ((inner ^ (row & 7)) * 16),
                    Ks + c * 16);
        }
    };
    auto stageV = [&](int t, int b) {
        char* Vs = smem + 16384 + b * 8192;
        #pragma unroll
        for (int it = 0; it < 2; ++it) {
            int c = it * 256 + tid;
            int row = c >> 3, inner = c & 7;   // row = d
            async16((const char*)vhT + (base + (size_t)row * 2048 + (size_t)t * 64) * 2 + ((inner ^ (row & 7)) * 16),
                    Vs + c * 16);
        }
    };

    // hoist Q B-fragments: lane holds Q[qrw + l31][ks*16 + hi*8 + 0..7]
    bf16x8 qf[4];
    #pragma unroll
    for (int ks = 0; ks < 4; ++ks)
        qf[ks] = *(const bf16x8*)((const char*)qh + (base + (size_t)(qrw + l31) * 64) * 2 + ks * 32 + hi * 16);

    f32x16 o[2];
    #pragma unroll
    for (int r = 0; r < 16; ++r) { o[0][r] = 0.f; o[1][r] = 0.f; }
    float m_run = -1e30f, l_run = 0.f;

    const int nkv = qt * 2 + 2;
    stageK(0, 0); stageV(0, 0);
    __syncthreads();

    for (int t = 0; t < nkv; ++t) {
        const int kv0 = t * 64;
        const int cur = t & 1;
        if (t + 1 < nkv) { stageK(t + 1, cur ^ 1); stageV(t + 1, cur ^ 1); }

        if (kv0 <= qrw + 31) {
            const char* Ks = smem + cur * 8192;
            const char* Vs = smem + 16384 + cur * 8192;

            // ---- QK^T (swapped): st[tt][r] = S[kv0 + tt*32 + (r&3)+8*(r>>2)+4*hi][qrw + l31]
            f32x16 st[2];
            #pragma unroll
            for (int r = 0; r < 16; ++r) { st[0][r] = 0.f; st[1][r] = 0.f; }
            #pragma unroll
            for (int tt = 0; tt < 2; ++tt)
                #pragma unroll
                for (int ks = 0; ks < 4; ++ks) {
                    int row = tt * 32 + l31;
                    int byte = (row * 128 + ks * 32 + hi * 16) ^ ((row & 7) << 4);
                    bf16x8 kf = *(const bf16x8*)(Ks + byte);
                    st[tt] = mfma32(kf, qf[ks], st[tt]);
                }

            // ---- causal mask (diagonal tiles only)
            if (kv0 + 63 > qrw) {
                #pragma unroll
                for (int tt = 0; tt < 2; ++tt)
                    #pragma unroll
                    for (int r = 0; r < 16; ++r) {
                        int kv = kv0 + tt * 32 + (r & 3) + 8 * (r >> 2) + 4 * hi;
                        if (kv > qrw + l31) st[tt][r] = -1e30f;
                    }
            }

            // ---- row max (lane-local + cross-half)
            float mx = st[0][0];
            #pragma unroll
            for (int tt = 0; tt < 2; ++tt)
                #pragma unroll
                for (int r = 0; r < 16; ++r) mx = fmaxf(mx, st[tt][r]);
            mx = fmaxf(mx, __shfl_xor(mx, 32));

            // ---- defer-max online softmax (T13, THR=8)
            if (!__all(mx - m_run <= 8.0f)) {
                float mn = fmaxf(m_run, mx);
                float corr = __expf(m_run - mn);
                l_run *= corr;
                m_run = mn;
                #pragma unroll
                for (int r = 0; r < 16; ++r) {
                    int qsrc = (r & 3) + 8 * (r >> 2) + 4 * hi;
                    float c2 = __shfl(corr, qsrc);
                    o[0][r] *= c2; o[1][r] *= c2;
                }
            }

            float sum = 0.f;
            #pragma unroll
            for (int tt = 0; tt < 2; ++tt)
                #pragma unroll
                for (int r = 0; r < 16; ++r) {
                    float p = __expf(st[tt][r] - m_run);
                    st[tt][r] = p;
                    sum += p;
                }
            sum += __shfl_xor(sum, 32);
            l_run += sum;

            // ---- pack P to bf16 words; exchange across halves
            unsigned Wd[2][8], Xw[2][8];
            #pragma unroll
            for (int tt = 0; tt < 2; ++tt)
                #pragma unroll
                for (int k = 0; k < 8; ++k) {
                    unsigned w;
                    asm("v_cvt_pk_bf16_f32 %0, %1, %2" : "=v"(w) : "v"(st[tt][2 * k]), "v"(st[tt][2 * k + 1]));
                    Wd[tt][k] = w;
                }
            #pragma unroll
            for (int tt = 0; tt < 2; ++tt)
                #pragma unroll
                for (int k = 0; k < 8; ++k)
                    Xw[tt][k] = __shfl_xor((int)Wd[tt][k], 32);

            // ---- PV: o[dt] += P[q][kv] * V[kv][d]
            #pragma unroll
            for (int ks = 0; ks < 4; ++ks) {
                const int t2 = ks >> 1, bse = (ks & 1) * 4;
                unsigned w0 = hi ? Xw[t2][bse + 2] : Wd[t2][bse + 0];
                unsigned w1 = hi ? Xw[t2][bse + 3] : Wd[t2][bse + 1];
                unsigned w2 = hi ? Wd[t2][bse + 2] : Xw[t2][bse + 0];
                unsigned w3 = hi ? Wd[t2][bse + 3] : Xw[t2][bse + 1];
                unsigned pw[4] = {w0, w1, w2, w3};
                bf16x8 pf = *(const bf16x8*)pw;
                #pragma unroll
                for (int dt = 0; dt < 2; ++dt) {
                    int row = dt * 32 + l31;
                    int byte = (row * 128 + ks * 32 + hi * 16) ^ ((row & 7) << 4);
                    bf16x8 vf = *(const bf16x8*)(Vs + byte);
                    o[dt] = mfma32(pf, vf, o[dt]);
                }
            }
        }
        __syncthreads();
    }

    // ---- epilogue: normalize, store [B][S][1024] bf16
    const int b = bh >> 4, h = bh & 15;
    float invl = 1.0f / l_run;
    #pragma unroll
    for (int r = 0; r < 16; ++r) {
        int qsrc = (r & 3) + 8 * (r >> 2) + 4 * hi;
        float iv = __shfl(invl, qsrc);
        int q = qrw + qsrc;
        size_t rowoff = ((size_t)(b * 2048 + q)) * 1024 + h * 64;
        yb[rowoff + l31]      = f2bf(o[0][r] * iv);
        yb[rowoff + 32 + l31] = f2bf(o[1][r] * iv);
    }
}

extern "C" void kernel_launch(void* const* d_in, const int* in_sizes, int n_in,
                              void* d_out, int out_size, void* d_ws, size_t ws_size,
                              hipStream_t stream)
{
    const size_t MD = 4096ull * 1024;   // B*S x d_model elements
    const size_t WD = 1024ull * 1024;
    ushort* ws  = (ushort*)d_ws;
    ushort* Qb  = ws;
    ushort* Kb  = Qb + MD;
    ushort* Vb  = Kb + MD;
    ushort* qhb = Vb + MD;
    ushort* khb = qhb + MD;
    ushort* vhT = khb + MD;
    ushort* WQb = vhT + MD;
    ushort* WKb = WQb + WD;
    ushort* WVb = WKb + WD;
    ushort* Wfb = WVb + WD;
    ushort* yb  = Qb;   // alias: Qb is dead after the QKV projection

    cvt7_kernel<<<dim3(4096, 7), 256, 0, stream>>>(
        (const float*)d_in[0], (const float*)d_in[1], (const float*)d_in[2],
        (const float*)d_in[3], (const float*)d_in[4], (const float*)d_in[5],
        (const float*)d_in[6],
        Qb, Kb, Vb, WQb, WKb, WVb, Wfb);

    gemm_qkv<<<dim3(96, 8), 256, 0, stream>>>(Qb, Kb, Vb, WQb, WKb, WVb, qhb, khb, vhT);
    attn_kernel<<<dim3(16, 32), 256, 0, stream>>>(qhb, khb, vhT, yb);
    gemm_fc<<<dim3(32, 8), 256, 0, stream>>>(yb, Wfb, (float*)d_out, (const float*)d_in[7]);
}